// Round 2
// baseline (899.445 us; speedup 1.0000x reference)
//
#include <hip/hip_runtime.h>
#include <hip/hip_cooperative_groups.h>

namespace cg = cooperative_groups;

#define C_    192
#define N_    32
#define H_    112
#define W_    112
#define HW    (H_ * W_)          // 12544
#define W4    28                 // float4s per row
#define PIX   (H_ * W4)          // 3136 float4s per plane
#define TPB   256
#define NBLK  1024               // 4 blocks/CU on 256 CUs; 6144/1024 = 6 planes/block
#define PLANES (N_ * C_)         // 6144
#define PPB   (PLANES / NBLK)    // 6

typedef float nat4 __attribute__((ext_vector_type(4)));

__device__ __forceinline__ void conv_row(const float* __restrict__ row, int j,
                                         float w0, float w1, float w2,
                                         float4& acc) {
    const float4 m = *(const float4*)(row + 4 * j);
    const float l = (j > 0)      ? row[4 * j - 1] : 0.0f;
    const float r = (j < W4 - 1) ? row[4 * j + 4] : 0.0f;
    acc.x = fmaf(w0, l,   fmaf(w1, m.x, fmaf(w2, m.y, acc.x)));
    acc.y = fmaf(w0, m.x, fmaf(w1, m.y, fmaf(w2, m.z, acc.y)));
    acc.z = fmaf(w0, m.y, fmaf(w1, m.z, fmaf(w2, m.w, acc.z)));
    acc.w = fmaf(w0, m.z, fmaf(w1, m.w, fmaf(w2, r,   acc.w)));
}

// 3x3 depthwise conv, zero padding, 4 horizontally-adjacent outputs.
// Conv bias b is omitted: it cancels exactly inside training-mode BN.
__device__ __forceinline__ float4 conv4(const float* __restrict__ plane,
                                        int h, int j, const float* wc) {
    float4 acc = {0.f, 0.f, 0.f, 0.f};
    if (h > 0)      conv_row(plane + (size_t)(h - 1) * W_, j, wc[0], wc[1], wc[2], acc);
                    conv_row(plane + (size_t)h       * W_, j, wc[3], wc[4], wc[5], acc);
    if (h < H_ - 1) conv_row(plane + (size_t)(h + 1) * W_, j, wc[6], wc[7], wc[8], acc);
    return acc;
}

__global__ __launch_bounds__(TPB, 4) void fused_kernel(
        const float* __restrict__ in,
        const float* __restrict__ w,
        const float* __restrict__ gamma,
        const float* __restrict__ beta,
        float* __restrict__ out,
        float* __restrict__ acc) {
    cg::grid_group grid = cg::this_grid();
    const int tid = threadIdx.x;
    const int bid = blockIdx.x;

    // --- zero the per-channel accumulators (ws is poisoned 0xAA every call) ---
    if (bid == 0)
        for (int i = tid; i < 2 * C_; i += TPB) acc[i] = 0.0f;
    grid.sync();

    __shared__ float ls[TPB / 64], lss[TPB / 64];

    // --- phase 1: per-channel sum / sumsq of the biasless conv output ---
    // Planes ordered c-major (pl = c*32 + n); block bid owns [bid*PPB, bid*PPB+PPB).
    for (int pl = bid * PPB; pl < bid * PPB + PPB; ++pl) {
        const int c = pl >> 5, n = pl & 31;
        const float* plane = in + (size_t)(n * C_ + c) * HW;
        float wc[9];
#pragma unroll
        for (int k = 0; k < 9; ++k) wc[k] = w[c * 9 + k];

        float s = 0.0f, ss = 0.0f;
        for (int p = tid; p < PIX; p += TPB) {
            const int h = p / W4, j = p - h * W4;
            const float4 y = conv4(plane, h, j, wc);
            s  += (y.x + y.y) + (y.z + y.w);
            ss += (y.x * y.x + y.y * y.y) + (y.z * y.z + y.w * y.w);
        }
#pragma unroll
        for (int off = 32; off > 0; off >>= 1) {
            s  += __shfl_down(s,  off, 64);
            ss += __shfl_down(ss, off, 64);
        }
        if ((tid & 63) == 0) { ls[tid >> 6] = s; lss[tid >> 6] = ss; }
        __syncthreads();
        if (tid == 0) {
            const float S  = (ls[0]  + ls[1])  + (ls[2]  + ls[3]);
            const float SS = (lss[0] + lss[1]) + (lss[2] + lss[3]);
            atomicAdd(&acc[c],      S);
            atomicAdd(&acc[C_ + c], SS);
        }
        __syncthreads();   // ls/lss reused next plane
    }

    grid.sync();

    // --- phase 2: recompute conv, normalize + ReLU6, NT-store ---
    // Reverse per-block plane order: the most-recently-read planes are still in
    // L3, so most phase-2 input reads avoid HBM. NT stores keep `out` from
    // evicting them.
    for (int pl = bid * PPB + PPB - 1; pl >= bid * PPB; --pl) {
        const int c = pl >> 5, n = pl & 31;
        const float* plane  = in  + (size_t)(n * C_ + c) * HW;
        float*       oplane = out + (size_t)(n * C_ + c) * HW;
        float wc[9];
#pragma unroll
        for (int k = 0; k < 9; ++k) wc[k] = w[c * 9 + k];

        const float M    = (float)N_ * (float)HW;
        const float mean = acc[c] / M;
        const float var  = fmaxf(acc[C_ + c] / M - mean * mean, 0.0f);
        const float sc   = gamma[c] * rsqrtf(var + 1e-5f);
        const float sh   = beta[c] - sc * mean;

        for (int p = tid; p < PIX; p += TPB) {
            const int h = p / W4, j = p - h * W4;
            const float4 y = conv4(plane, h, j, wc);
            nat4 z;
            z.x = fminf(fmaxf(fmaf(sc, y.x, sh), 0.0f), 6.0f);
            z.y = fminf(fmaxf(fmaf(sc, y.y, sh), 0.0f), 6.0f);
            z.z = fminf(fmaxf(fmaf(sc, y.z, sh), 0.0f), 6.0f);
            z.w = fminf(fmaxf(fmaf(sc, y.w, sh), 0.0f), 6.0f);
            __builtin_nontemporal_store(z, (nat4*)(oplane + 4 * p));
        }
    }
}

extern "C" void kernel_launch(void* const* d_in, const int* in_sizes, int n_in,
                              void* d_out, int out_size, void* d_ws, size_t ws_size,
                              hipStream_t stream) {
    const float* in    = (const float*)d_in[0];
    const float* w     = (const float*)d_in[1];
    // d_in[2] = conv bias: cancels exactly in training-mode BN — unused.
    const float* gamma = (const float*)d_in[3];
    const float* beta  = (const float*)d_in[4];
    float* out = (float*)d_out;
    float* acc = (float*)d_ws;   // 2*C_ floats: sum, sumsq

    void* args[] = {(void*)&in, (void*)&w, (void*)&gamma, (void*)&beta,
                    (void*)&out, (void*)&acc};
    hipLaunchCooperativeKernel((void*)fused_kernel, dim3(NBLK), dim3(TPB),
                               args, 0, stream);
}